// Round 10
// baseline (141.811 us; speedup 1.0000x reference)
//
#include <hip/hip_runtime.h>

// Problem constants (static per reference setup_inputs)
#define BB     16
#define HH     128
#define WW     8192
#define N_MAXC 128
#define W_OUTC 6271
#define SEP_CLASS 2.0f

// d_out layout (all float32): x_new [B*H*W_OUT] | xi_new [B*N_MAX*2] | xl_new [B*W_OUT]
#define X_ELEMS (BB * HH * W_OUTC)            // 12,843,008
#define XI_OFF  (X_ELEMS)
#define XL_OFF  (X_ELEMS + BB * N_MAXC * 2)

#define WS_INTS (BB * 2 * N_MAXC)             // sn+en per batch (16KB)

// tb_main roles: copy = 8 chirpgroups(16) x 8 rowgroups(16) x 16 b
#define NCOPY 1024
#define NFILL 128
#define NAUX  208
#define NBLK  (NCOPY + NFILL + NAUX)
#define KPT   12                              // 16r x 16c x 12chunks = 3072 = 12*256

typedef float vf4u __attribute__((ext_vector_type(4), aligned(4)));

// Reference map_col (verified R2-R9): >=0 src | -1 sep | -2 zero.
__device__ __forceinline__ int map_col_lds(int t, int Nb,
                                           const int* s_s0, const int* s_e0,
                                           const int* s_sn, const int* s_en) {
    int lo = 0, hi = Nb;
    while (lo < hi) { int mid = (lo + hi) >> 1; if (s_en[mid] <= t) lo = mid + 1; else hi = mid; }
    const int i  = lo;
    const int ic = (i < N_MAXC - 1) ? i : (N_MAXC - 1);
    if (i < Nb) {
        int sn = s_sn[ic], en = s_en[ic];
        if (t >= sn && en > sn && s_e0[ic] > s_s0[ic]) {
            int src = s_s0[ic] + (t - sn);
            return src < 0 ? 0 : (src > WW - 1 ? WW - 1 : src);
        }
    }
    if (i >= 1) {
        int ep = s_en[i - 1];
        if (t == ep && (i - 1) < (Nb - 1) && ep < WW) return -1;
    }
    return -2;
}

// ---------------- kernel 1: scan -> ws (sn,en) + xi_new (verified R8/R9) ----------------
__global__ __launch_bounds__(128) void tb_scan(const int* __restrict__ xi,
                                               const int* __restrict__ Nv,
                                               float* __restrict__ out,
                                               int* __restrict__ ws) {
    __shared__ int s_scan[N_MAXC];
    const int b   = blockIdx.x;
    const int tid = threadIdx.x;
    const int Nb  = Nv[b];
    int2 se = ((const int2*)xi)[b * N_MAXC + tid];
    int w = se.y - se.x; if (w < 0) w = 0;
    const int wv = (tid < Nb) ? w : 0;
    s_scan[tid] = wv;
    __syncthreads();
    #pragma unroll
    for (int off = 1; off < N_MAXC; off <<= 1) {
        int v = (tid >= off) ? s_scan[tid - off] : 0;
        __syncthreads();
        s_scan[tid] += v;
        __syncthreads();
    }
    const int c  = s_scan[tid];
    const int sn = c - wv + tid;
    const int en = c + tid;
    ws[b * 2 * N_MAXC + tid]          = sn;
    ws[b * 2 * N_MAXC + N_MAXC + tid] = en;
    const bool valid = tid < Nb;
    out[XI_OFF + (b * N_MAXC + tid) * 2 + 0] = valid ? (float)sn : 0.0f;
    out[XI_OFF + (b * N_MAXC + tid) * 2 + 1] = valid ? (float)en : 0.0f;
}

// ---------------- kernel 2: role-dispatched main (NT stores, 12-deep) ----------------
__global__ __launch_bounds__(256) void tb_main(const float* __restrict__ x,
                                               const int* __restrict__ xi,
                                               const int* __restrict__ Nv,
                                               const int* __restrict__ xl,
                                               const float* __restrict__ sep_param,
                                               const int* __restrict__ ws,
                                               float* __restrict__ out) {
    __shared__ int s_buf[512];                 // union across roles (2KB)
    const int bid = blockIdx.x;
    const int tid = threadIdx.x;

    if (bid < NCOPY) {
        // ======== copy role: 16 chirps x 16 rows, NT float4 chirp copy ========
        const int cg = bid >> 7;               // 0..7 chirp group (16 chirps)
        const int rg = (bid >> 4) & 7;         // 0..7 row group (16 rows)
        const int b  = bid & 15;
        const int Nb = Nv[b];
        int* s_s0 = s_buf;       // [16]
        int* s_sn = s_buf + 16;  // [16]
        int* s_w  = s_buf + 32;  // [16]
        int* s_sp = s_buf + 48;  // [16] separator col (or -1)
        if (tid < 16) {
            const int i  = cg * 16 + tid;
            const int sn = ws[b * 2 * N_MAXC + i];
            const int en = ws[b * 2 * N_MAXC + N_MAXC + i];
            int2 se = ((const int2*)xi)[b * N_MAXC + i];
            int w = se.y - se.x; if (w < 0) w = 0;
            const bool valid = (i < Nb) && (w > 0);
            s_s0[tid] = valid ? se.x : 0;
            s_sn[tid] = valid ? sn   : 0;
            s_w[tid]  = valid ? w    : 0;
            s_sp[tid] = (i < Nb - 1 && en < WW) ? en : -1;
        }
        __syncthreads();

        const int h0 = rg * 16;
        const float sep = sep_param[0];
        const float* xb = x   + ((size_t)(b * HH + h0) << 13);
        float*       ob = out + (size_t)(b * HH + h0) * W_OUTC;

        // 3072 units = 16 rows x 16 chirps x 12 chunks; 12 per thread, phase-batched
        unsigned osrc[KPT], odst[KPT], urem[KPT];
        bool ua[KPT], uf[KPT];
        #pragma unroll
        for (int p = 0; p < KPT; ++p) {
            const unsigned unit = (unsigned)tid + (unsigned)p * 256u;
            const unsigned jr = unit / 12u;          // 0..255
            const unsigned k  = unit - jr * 12u;     // chunk 0..11
            const unsigned j  = jr & 15u;            // chirp 0..15
            const unsigned r  = jr >> 4;             // row 0..15
            const unsigned w  = (unsigned)s_w[j];
            unsigned sc = (unsigned)s_s0[j] + 4u * k;
            if (sc > (unsigned)(WW - 4)) sc = WW - 4;      // OOB guard (never hit, real data)
            osrc[p] = (r << 13) + sc;
            odst[p] = r * (unsigned)W_OUTC + (unsigned)s_sn[j] + 4u * k;
            ua[p]   = (4u * k < w);
            uf[p]   = (4u * k + 4u <= w);
            urem[p] = w - 4u * k;
        }
        vf4u vv[KPT];
        #pragma unroll
        for (int p = 0; p < KPT; ++p) {
            if (ua[p]) vv[p] = __builtin_nontemporal_load((const vf4u*)(xb + osrc[p]));
        }
        #pragma unroll
        for (int p = 0; p < KPT; ++p) {
            if (uf[p]) {
                __builtin_nontemporal_store(vv[p], (vf4u*)(ob + odst[p]));
            } else if (ua[p]) {                       // ragged tail chunk (w%4)
                float* dd = ob + odst[p];
                if (urem[p] > 0) __builtin_nontemporal_store(vv[p].x, dd + 0);
                if (urem[p] > 1) __builtin_nontemporal_store(vv[p].y, dd + 1);
                if (urem[p] > 2) __builtin_nontemporal_store(vv[p].z, dd + 2);
            }
        }
        // separators: 16 chirps x 16 rows = 256 predicated scalar NT stores
        {
            const int j = tid & 15, r = tid >> 4;
            const int pos = s_sp[j];
            if (pos >= 0) __builtin_nontemporal_store(sep, ob + (size_t)r * W_OUTC + pos);
        }
    } else if (bid < NCOPY + NFILL) {
        // ======== fill role: zero tail [en_{Nb-1}, W_OUT) for 16 rows ========
        const int fid = bid - NCOPY;
        const int rg  = fid >> 4;              // 0..7
        const int b   = fid & 15;
        const int Nb  = Nv[b];
        int zstart = (Nb > 0) ? ws[b * 2 * N_MAXC + N_MAXC + (Nb - 1)] : 0;
        if (zstart < 0) zstart = 0;
        float* ob = out + (size_t)(b * HH + rg * 16) * W_OUTC;
        for (int r = 0; r < 16; ++r) {
            float* orow = ob + (size_t)r * W_OUTC;
            for (int t = zstart + tid; t < W_OUTC; t += 256)
                __builtin_nontemporal_store(0.0f, orow + t);
        }
    } else {
        // ======== aux role: xl_new via verified map_col ========
        const int aid  = bid - NCOPY - NFILL;  // 0..207
        const int tile = aid % 13;
        const int b    = aid / 13;
        const int Nb   = Nv[b];
        int* a_s0 = s_buf;        // [128]
        int* a_e0 = s_buf + 128;
        int* a_sn = s_buf + 256;
        int* a_en = s_buf + 384;
        if (tid < N_MAXC) {
            int2 se = ((const int2*)xi)[b * N_MAXC + tid];
            a_s0[tid] = se.x; a_e0[tid] = se.y;
            a_sn[tid] = ws[b * 2 * N_MAXC + tid];
            a_en[tid] = ws[b * 2 * N_MAXC + N_MAXC + tid];
        }
        __syncthreads();
        #pragma unroll
        for (int q = 0; q < 2; ++q) {
            const int t = tile * 512 + tid + q * 256;
            if (t < W_OUTC) {
                const int m = map_col_lds(t, Nb, a_s0, a_e0, a_sn, a_en);
                float v = (m >= 0) ? (float)xl[b * WW + m] : ((m == -1) ? SEP_CLASS : 0.0f);
                out[XL_OFF + b * W_OUTC + t] = v;
            }
        }
    }
}

// ---------------- fallback (no ws): round-7 fused kernel (verified) ----------------
#define TCOLS 512
#define HROWS 16
#define NTILE 13
typedef int vi4 __attribute__((ext_vector_type(4)));

__global__ __launch_bounds__(256, 4) void tb_fused(const float* __restrict__ x,
                                                   const int* __restrict__ xi,
                                                   const int* __restrict__ Nv,
                                                   const int* __restrict__ xl,
                                                   const float* __restrict__ sep_param,
                                                   float* __restrict__ out) {
    __shared__ int s_s0[N_MAXC], s_e0[N_MAXC], s_scan[N_MAXC], s_sn[N_MAXC], s_en[N_MAXC];
    __shared__ __align__(16) int s_map[TCOLS];
    const int t0  = blockIdx.x * TCOLS;
    const int h0  = blockIdx.y * HROWS;
    const int b   = blockIdx.z;
    const int tid = threadIdx.x;
    const int Nb  = Nv[b];
    int wv = 0;
    if (tid < N_MAXC) {
        int2 se = ((const int2*)xi)[b * N_MAXC + tid];
        s_s0[tid] = se.x; s_e0[tid] = se.y;
        int w = se.y - se.x; if (w < 0) w = 0;
        wv = (tid < Nb) ? w : 0;
        s_scan[tid] = wv;
    }
    __syncthreads();
    #pragma unroll
    for (int off = 1; off < N_MAXC; off <<= 1) {
        int v = 0;
        if (tid < N_MAXC && tid >= off) v = s_scan[tid - off];
        __syncthreads();
        if (tid < N_MAXC) s_scan[tid] += v;
        __syncthreads();
    }
    if (tid < N_MAXC) {
        int c = s_scan[tid];
        s_sn[tid] = c - wv + tid;
        s_en[tid] = c + tid;
    }
    __syncthreads();
    #pragma unroll
    for (int q = 0; q < 2; ++q) {
        const int j = tid + q * 256;
        const int t = t0 + j;
        s_map[j] = (t < W_OUTC) ? map_col_lds(t, Nb, s_s0, s_e0, s_sn, s_en) : -2;
    }
    if (blockIdx.y == 0 && blockIdx.x == 0 && tid < N_MAXC) {
        const bool valid = tid < Nb;
        out[XI_OFF + (b * N_MAXC + tid) * 2 + 0] = valid ? (float)s_sn[tid] : 0.0f;
        out[XI_OFF + (b * N_MAXC + tid) * 2 + 1] = valid ? (float)s_en[tid] : 0.0f;
    }
    __syncthreads();
    if (blockIdx.y == 0) {
        #pragma unroll
        for (int q = 0; q < 2; ++q) {
            const int j = tid + q * 256;
            const int t = t0 + j;
            if (t < W_OUTC) {
                const int m = s_map[j];
                float v = (m >= 0) ? (float)xl[b * WW + m] : ((m == -1) ? SEP_CLASS : 0.0f);
                out[XL_OFF + b * W_OUTC + t] = v;
            }
        }
    }
    const float sep = sep_param[0];
    const int   c   = tid & 127;
    const int   rb  = tid >> 7;
    const vi4   mv  = ((const vi4*)s_map)[c];
    const int   tA  = t0 + 4 * c;
    const float* xb = x   + ((size_t)b << 20);
    float*       ob = out + (size_t)b * (HH * W_OUTC);
    const unsigned a0 = (mv.x >= 0) ? (unsigned)mv.x : 0u;
    const unsigned a1 = (mv.y >= 0) ? (unsigned)mv.y : 0u;
    const unsigned a2 = (mv.z >= 0) ? (unsigned)mv.z : 0u;
    const unsigned a3 = (mv.w >= 0) ? (unsigned)mv.w : 0u;
    const float f0 = (mv.x == -1) ? sep : 0.0f;
    const float f1 = (mv.y == -1) ? sep : 0.0f;
    const float f2 = (mv.z == -1) ? sep : 0.0f;
    const float f3 = (mv.w == -1) ? sep : 0.0f;
    if (tA + 3 < W_OUTC) {
        #pragma unroll
        for (int rr = 0; rr < HROWS / 2; ++rr) {
            const int h = h0 + rb + rr * 2;
            const float* xr = xb + ((size_t)h << 13);
            float* orow = ob + (size_t)h * W_OUTC + tA;
            const float v0 = (mv.x >= 0) ? xr[a0] : f0;
            const float v1 = (mv.y >= 0) ? xr[a1] : f1;
            const float v2 = (mv.z >= 0) ? xr[a2] : f2;
            const float v3 = (mv.w >= 0) ? xr[a3] : f3;
            orow[0] = v0; orow[1] = v1; orow[2] = v2; orow[3] = v3;
        }
    } else if (tA < W_OUTC) {
        const int nrem = W_OUTC - tA;
        #pragma unroll
        for (int rr = 0; rr < HROWS / 2; ++rr) {
            const int h = h0 + rb + rr * 2;
            const float* xr = xb + ((size_t)h << 13);
            float* orow = ob + (size_t)h * W_OUTC + tA;
            if (nrem > 0) orow[0] = (mv.x >= 0) ? xr[a0] : f0;
            if (nrem > 1) orow[1] = (mv.y >= 0) ? xr[a1] : f1;
            if (nrem > 2) orow[2] = (mv.z >= 0) ? xr[a2] : f2;
        }
    }
}

extern "C" void kernel_launch(void* const* d_in, const int* in_sizes, int n_in,
                              void* d_out, int out_size, void* d_ws, size_t ws_size,
                              hipStream_t stream) {
    const float* x   = (const float*)d_in[0];
    const int*   xi  = (const int*)  d_in[1];
    const int*   Nv  = (const int*)  d_in[2];
    const int*   xl  = (const int*)  d_in[3];
    const float* sep = (const float*)d_in[4];
    float*       out = (float*)d_out;

    if (d_ws && ws_size >= WS_INTS * sizeof(int)) {
        int* ws = (int*)d_ws;
        tb_scan<<<dim3(BB), dim3(128), 0, stream>>>(xi, Nv, out, ws);
        tb_main<<<dim3(NBLK), dim3(256), 0, stream>>>(x, xi, Nv, xl, sep, ws, out);
    } else {
        dim3 grid(NTILE, HH / HROWS, BB);
        tb_fused<<<grid, dim3(256), 0, stream>>>(x, xi, Nv, xl, sep, out);
    }
}

// Round 12
// 136.571 us; speedup vs baseline: 1.0384x; 1.0384x over previous
//
#include <hip/hip_runtime.h>

// Problem constants (static per reference setup_inputs)
#define BB     16
#define HH     128
#define WW     8192
#define N_MAXC 128
#define W_OUTC 6271
#define SEP_CLASS 2.0f

// d_out layout (all float32): x_new [B*H*W_OUT] | xi_new [B*N_MAX*2] | xl_new [B*W_OUT]
#define X_ELEMS (BB * HH * W_OUTC)            // 12,843,008
#define XI_OFF  (X_ELEMS)
#define XL_OFF  (X_ELEMS + BB * N_MAXC * 2)

#define WS_INTS (BB * 2 * N_MAXC)             // sn+en per batch (16KB)

// tb_main roles: copy = 8 chirpgroups(16) x 8 rowgroups(16) x 16 b
#define NCOPY 1024
#define NFILL 128
#define NAUX  208
#define NBLK  (NCOPY + NFILL + NAUX)
#define KPT   12                              // 16r x 16c x 12chunks = 3072 = 12*256

typedef float vf4  __attribute__((ext_vector_type(4)));
typedef float vf4u __attribute__((ext_vector_type(4), aligned(4)));

// Reference map_col (verified R2-R10): >=0 src | -1 sep | -2 zero.
__device__ __forceinline__ int map_col_lds(int t, int Nb,
                                           const int* s_s0, const int* s_e0,
                                           const int* s_sn, const int* s_en) {
    int lo = 0, hi = Nb;
    while (lo < hi) { int mid = (lo + hi) >> 1; if (s_en[mid] <= t) lo = mid + 1; else hi = mid; }
    const int i  = lo;
    const int ic = (i < N_MAXC - 1) ? i : (N_MAXC - 1);
    if (i < Nb) {
        int sn = s_sn[ic], en = s_en[ic];
        if (t >= sn && en > sn && s_e0[ic] > s_s0[ic]) {
            int src = s_s0[ic] + (t - sn);
            return src < 0 ? 0 : (src > WW - 1 ? WW - 1 : src);
        }
    }
    if (i >= 1) {
        int ep = s_en[i - 1];
        if (t == ep && (i - 1) < (Nb - 1) && ep < WW) return -1;
    }
    return -2;
}

// ---------------- kernel 1: scan -> ws (sn,en) + xi_new (verified R8-R10) ----------------
__global__ __launch_bounds__(128) void tb_scan(const int* __restrict__ xi,
                                               const int* __restrict__ Nv,
                                               float* __restrict__ out,
                                               int* __restrict__ ws) {
    __shared__ int s_scan[N_MAXC];
    const int b   = blockIdx.x;
    const int tid = threadIdx.x;
    const int Nb  = Nv[b];
    int2 se = ((const int2*)xi)[b * N_MAXC + tid];
    int w = se.y - se.x; if (w < 0) w = 0;
    const int wv = (tid < Nb) ? w : 0;
    s_scan[tid] = wv;
    __syncthreads();
    #pragma unroll
    for (int off = 1; off < N_MAXC; off <<= 1) {
        int v = (tid >= off) ? s_scan[tid - off] : 0;
        __syncthreads();
        s_scan[tid] += v;
        __syncthreads();
    }
    const int c  = s_scan[tid];
    const int sn = c - wv + tid;
    const int en = c + tid;
    ws[b * 2 * N_MAXC + tid]          = sn;
    ws[b * 2 * N_MAXC + N_MAXC + tid] = en;
    const bool valid = tid < Nb;
    out[XI_OFF + (b * N_MAXC + tid) * 2 + 0] = valid ? (float)sn : 0.0f;
    out[XI_OFF + (b * N_MAXC + tid) * 2 + 1] = valid ? (float)en : 0.0f;
}

// ---------------- kernel 2: role-dispatched main (asm-forced 12-deep loads) ----------------
__global__ __launch_bounds__(256) void tb_main(const float* __restrict__ x,
                                               const int* __restrict__ xi,
                                               const int* __restrict__ Nv,
                                               const int* __restrict__ xl,
                                               const float* __restrict__ sep_param,
                                               const int* __restrict__ ws,
                                               float* __restrict__ out) {
    __shared__ int s_buf[512];                 // union across roles (2KB)
    const int bid = blockIdx.x;
    const int tid = threadIdx.x;

    if (bid < NCOPY) {
        // ======== copy role: 16 chirps x 16 rows, forced-deep float4 chirp copy ========
        const int cg = bid >> 7;               // 0..7 chirp group (16 chirps)
        const int rg = (bid >> 4) & 7;         // 0..7 row group (16 rows)
        const int b  = bid & 15;
        const int Nb = Nv[b];
        int* s_s0 = s_buf;       // [16]
        int* s_sn = s_buf + 16;  // [16]
        int* s_w  = s_buf + 32;  // [16]
        int* s_sp = s_buf + 48;  // [16] separator col (or -1)
        if (tid < 16) {
            const int i  = cg * 16 + tid;
            const int sn = ws[b * 2 * N_MAXC + i];
            const int en = ws[b * 2 * N_MAXC + N_MAXC + i];
            int2 se = ((const int2*)xi)[b * N_MAXC + i];
            int w = se.y - se.x; if (w < 0) w = 0;
            const bool valid = (i < Nb) && (w > 0);
            s_s0[tid] = valid ? se.x : 0;
            s_sn[tid] = valid ? sn   : 0;
            s_w[tid]  = valid ? w    : 0;
            s_sp[tid] = (i < Nb - 1 && en < WW) ? en : -1;
        }
        __syncthreads();

        const int h0 = rg * 16;
        const float sep = sep_param[0];
        const float* xb = x   + ((size_t)(b * HH + h0) << 13);
        float*       ob = out + (size_t)(b * HH + h0) * W_OUTC;

        // 3072 units = 16 rows x 16 chirps x 12 chunks; 12 per thread, phase-batched
        unsigned odst[KPT], urem[KPT];
        const float* ap[KPT];
        bool ua[KPT], uf[KPT];
        #pragma unroll
        for (int p = 0; p < KPT; ++p) {
            const unsigned unit = (unsigned)tid + (unsigned)p * 256u;
            const unsigned jr = unit / 12u;          // 0..255
            const unsigned k  = unit - jr * 12u;     // chunk 0..11
            const unsigned j  = jr & 15u;            // chirp 0..15
            const unsigned r  = jr >> 4;             // row 0..15
            const unsigned w  = (unsigned)s_w[j];
            unsigned sc = (unsigned)s_s0[j] + 4u * k;
            if (sc > (unsigned)(WW - 4)) sc = WW - 4;      // OOB guard (never hit, real data)
            ap[p]   = xb + ((size_t)r << 13) + sc;
            odst[p] = r * (unsigned)W_OUTC + (unsigned)s_sn[j] + 4u * k;
            ua[p]   = (4u * k < w);
            uf[p]   = (4u * k + 4u <= w);
            urem[p] = w - 4u * k;
        }
        // forced-live load batch: asm outputs must stay allocated -> 12 loads in flight
        vf4 vv[KPT];
        #pragma unroll
        for (int p = 0; p < KPT; ++p) {
            asm volatile("global_load_dwordx4 %0, %1, off"
                         : "=v"(vv[p]) : "v"(ap[p]));
        }
        asm volatile("s_waitcnt vmcnt(0)" ::: "memory");
        __builtin_amdgcn_sched_barrier(0);      // rule #18: pin uses after the wait
        #pragma unroll
        for (int p = 0; p < KPT; ++p) {
            if (uf[p]) {
                __builtin_nontemporal_store((vf4u)vv[p], (vf4u*)(ob + odst[p]));
            } else if (ua[p]) {                       // ragged tail chunk (w%4)
                float* dd = ob + odst[p];
                if (urem[p] > 0) __builtin_nontemporal_store(vv[p].x, dd + 0);
                if (urem[p] > 1) __builtin_nontemporal_store(vv[p].y, dd + 1);
                if (urem[p] > 2) __builtin_nontemporal_store(vv[p].z, dd + 2);
            }
        }
        // separators: 16 chirps x 16 rows = 256 predicated scalar NT stores
        {
            const int j = tid & 15, r = tid >> 4;
            const int pos = s_sp[j];
            if (pos >= 0) __builtin_nontemporal_store(sep, ob + (size_t)r * W_OUTC + pos);
        }
    } else if (bid < NCOPY + NFILL) {
        // ======== fill role: zero tail [en_{Nb-1}, W_OUT) for 16 rows ========
        const int fid = bid - NCOPY;
        const int rg  = fid >> 4;              // 0..7
        const int b   = fid & 15;
        const int Nb  = Nv[b];
        int zstart = (Nb > 0) ? ws[b * 2 * N_MAXC + N_MAXC + (Nb - 1)] : 0;
        if (zstart < 0) zstart = 0;
        float* ob = out + (size_t)(b * HH + rg * 16) * W_OUTC;
        for (int r = 0; r < 16; ++r) {
            float* orow = ob + (size_t)r * W_OUTC;
            for (int t = zstart + tid; t < W_OUTC; t += 256)
                __builtin_nontemporal_store(0.0f, orow + t);
        }
    } else {
        // ======== aux role: xl_new via verified map_col ========
        const int aid  = bid - NCOPY - NFILL;  // 0..207
        const int tile = aid % 13;
        const int b    = aid / 13;
        const int Nb   = Nv[b];
        int* a_s0 = s_buf;        // [128]
        int* a_e0 = s_buf + 128;
        int* a_sn = s_buf + 256;
        int* a_en = s_buf + 384;
        if (tid < N_MAXC) {
            int2 se = ((const int2*)xi)[b * N_MAXC + tid];
            a_s0[tid] = se.x; a_e0[tid] = se.y;
            a_sn[tid] = ws[b * 2 * N_MAXC + tid];
            a_en[tid] = ws[b * 2 * N_MAXC + N_MAXC + tid];
        }
        __syncthreads();
        #pragma unroll
        for (int q = 0; q < 2; ++q) {
            const int t = tile * 512 + tid + q * 256;
            if (t < W_OUTC) {
                const int m = map_col_lds(t, Nb, a_s0, a_e0, a_sn, a_en);
                float v = (m >= 0) ? (float)xl[b * WW + m] : ((m == -1) ? SEP_CLASS : 0.0f);
                out[XL_OFF + b * W_OUTC + t] = v;
            }
        }
    }
}

// ---------------- fallback (no ws): round-7 fused kernel (verified) ----------------
#define TCOLS 512
#define HROWS 16
#define NTILE 13
typedef int vi4 __attribute__((ext_vector_type(4)));

__global__ __launch_bounds__(256, 4) void tb_fused(const float* __restrict__ x,
                                                   const int* __restrict__ xi,
                                                   const int* __restrict__ Nv,
                                                   const int* __restrict__ xl,
                                                   const float* __restrict__ sep_param,
                                                   float* __restrict__ out) {
    __shared__ int s_s0[N_MAXC], s_e0[N_MAXC], s_scan[N_MAXC], s_sn[N_MAXC], s_en[N_MAXC];
    __shared__ __align__(16) int s_map[TCOLS];
    const int t0  = blockIdx.x * TCOLS;
    const int h0  = blockIdx.y * HROWS;
    const int b   = blockIdx.z;
    const int tid = threadIdx.x;
    const int Nb  = Nv[b];
    int wv = 0;
    if (tid < N_MAXC) {
        int2 se = ((const int2*)xi)[b * N_MAXC + tid];
        s_s0[tid] = se.x; s_e0[tid] = se.y;
        int w = se.y - se.x; if (w < 0) w = 0;
        wv = (tid < Nb) ? w : 0;
        s_scan[tid] = wv;
    }
    __syncthreads();
    #pragma unroll
    for (int off = 1; off < N_MAXC; off <<= 1) {
        int v = 0;
        if (tid < N_MAXC && tid >= off) v = s_scan[tid - off];
        __syncthreads();
        if (tid < N_MAXC) s_scan[tid] += v;
        __syncthreads();
    }
    if (tid < N_MAXC) {
        int c = s_scan[tid];
        s_sn[tid] = c - wv + tid;
        s_en[tid] = c + tid;
    }
    __syncthreads();
    #pragma unroll
    for (int q = 0; q < 2; ++q) {
        const int j = tid + q * 256;
        const int t = t0 + j;
        s_map[j] = (t < W_OUTC) ? map_col_lds(t, Nb, s_s0, s_e0, s_sn, s_en) : -2;
    }
    if (blockIdx.y == 0 && blockIdx.x == 0 && tid < N_MAXC) {
        const bool valid = tid < Nb;
        out[XI_OFF + (b * N_MAXC + tid) * 2 + 0] = valid ? (float)s_sn[tid] : 0.0f;
        out[XI_OFF + (b * N_MAXC + tid) * 2 + 1] = valid ? (float)s_en[tid] : 0.0f;
    }
    __syncthreads();
    if (blockIdx.y == 0) {
        #pragma unroll
        for (int q = 0; q < 2; ++q) {
            const int j = tid + q * 256;
            const int t = t0 + j;
            if (t < W_OUTC) {
                const int m = s_map[j];
                float v = (m >= 0) ? (float)xl[b * WW + m] : ((m == -1) ? SEP_CLASS : 0.0f);
                out[XL_OFF + b * W_OUTC + t] = v;
            }
        }
    }
    const float sep = sep_param[0];
    const int   c   = tid & 127;
    const int   rb  = tid >> 7;
    const vi4   mv  = ((const vi4*)s_map)[c];
    const int   tA  = t0 + 4 * c;
    const float* xb = x   + ((size_t)b << 20);
    float*       ob = out + (size_t)b * (HH * W_OUTC);
    const unsigned a0 = (mv.x >= 0) ? (unsigned)mv.x : 0u;
    const unsigned a1 = (mv.y >= 0) ? (unsigned)mv.y : 0u;
    const unsigned a2 = (mv.z >= 0) ? (unsigned)mv.z : 0u;
    const unsigned a3 = (mv.w >= 0) ? (unsigned)mv.w : 0u;
    const float f0 = (mv.x == -1) ? sep : 0.0f;
    const float f1 = (mv.y == -1) ? sep : 0.0f;
    const float f2 = (mv.z == -1) ? sep : 0.0f;
    const float f3 = (mv.w == -1) ? sep : 0.0f;
    if (tA + 3 < W_OUTC) {
        #pragma unroll
        for (int rr = 0; rr < HROWS / 2; ++rr) {
            const int h = h0 + rb + rr * 2;
            const float* xr = xb + ((size_t)h << 13);
            float* orow = ob + (size_t)h * W_OUTC + tA;
            const float v0 = (mv.x >= 0) ? xr[a0] : f0;
            const float v1 = (mv.y >= 0) ? xr[a1] : f1;
            const float v2 = (mv.z >= 0) ? xr[a2] : f2;
            const float v3 = (mv.w >= 0) ? xr[a3] : f3;
            orow[0] = v0; orow[1] = v1; orow[2] = v2; orow[3] = v3;
        }
    } else if (tA < W_OUTC) {
        const int nrem = W_OUTC - tA;
        #pragma unroll
        for (int rr = 0; rr < HROWS / 2; ++rr) {
            const int h = h0 + rb + rr * 2;
            const float* xr = xb + ((size_t)h << 13);
            float* orow = ob + (size_t)h * W_OUTC + tA;
            if (nrem > 0) orow[0] = (mv.x >= 0) ? xr[a0] : f0;
            if (nrem > 1) orow[1] = (mv.y >= 0) ? xr[a1] : f1;
            if (nrem > 2) orow[2] = (mv.z >= 0) ? xr[a2] : f2;
        }
    }
}

extern "C" void kernel_launch(void* const* d_in, const int* in_sizes, int n_in,
                              void* d_out, int out_size, void* d_ws, size_t ws_size,
                              hipStream_t stream) {
    const float* x   = (const float*)d_in[0];
    const int*   xi  = (const int*)  d_in[1];
    const int*   Nv  = (const int*)  d_in[2];
    const int*   xl  = (const int*)  d_in[3];
    const float* sep = (const float*)d_in[4];
    float*       out = (float*)d_out;

    if (d_ws && ws_size >= WS_INTS * sizeof(int)) {
        int* ws = (int*)d_ws;
        tb_scan<<<dim3(BB), dim3(128), 0, stream>>>(xi, Nv, out, ws);
        tb_main<<<dim3(NBLK), dim3(256), 0, stream>>>(x, xi, Nv, xl, sep, ws, out);
    } else {
        dim3 grid(NTILE, HH / HROWS, BB);
        tb_fused<<<grid, dim3(256), 0, stream>>>(x, xi, Nv, xl, sep, out);
    }
}